// Round 8
// baseline (734.645 us; speedup 1.0000x reference)
//
#include <hip/hip_runtime.h>
#include <math.h>

#define BATCH 8
#define CDIM 768
#define NTOK 1024
#define NH 12
#define HDIM 64

typedef __attribute__((ext_vector_type(8))) short bf16x8;
typedef __attribute__((ext_vector_type(4))) float f32x4;

__device__ inline short f2bf(float f) {
    union { float f; unsigned u; } v; v.f = f;
    unsigned r = (v.u + 0x7FFF + ((v.u >> 16) & 1)) >> 16;
    return (short)r;
}

// async global->LDS DMA, 16 B per lane; lptr must be the WAVE-uniform base,
// lane l writes lptr + l*16 bytes (m97 pattern).
__device__ inline void async_copy16(const short* g, short* l) {
    __builtin_amdgcn_global_load_lds(
        (const __attribute__((address_space(1))) void*)g,
        (__attribute__((address_space(3))) void*)l, 16, 0, 0);
}

// ---------------- transpose [B,C,N] -> [B,N,C], fp32 + bf16 mirror ----------------
__global__ void k_transpose_in(const float* __restrict__ dec, float* __restrict__ x,
                               short* __restrict__ xb) {
    __shared__ float tile[32][33];
    int b = blockIdx.z;
    int n0 = blockIdx.x * 32;
    int c0 = blockIdx.y * 32;
    int tx = threadIdx.x, ty = threadIdx.y;
#pragma unroll
    for (int r = 0; r < 4; ++r) {
        int c = c0 + ty + r * 8;
        tile[ty + r * 8][tx] = dec[((size_t)b * CDIM + c) * NTOK + n0 + tx];
    }
    __syncthreads();
#pragma unroll
    for (int r = 0; r < 4; ++r) {
        int n = n0 + ty + r * 8;
        float val = tile[tx][ty + r * 8];
        size_t idx = ((size_t)b * NTOK + n) * CDIM + c0 + tx;
        x[idx] = val;
        xb[idx] = f2bf(val);
    }
}

// ---------------- weight transpose fp32 [R,C] -> bf16 [C,R] ----------------
__global__ void k_wtrans(const float* __restrict__ src, short* __restrict__ dst,
                         int R, int C) {
    __shared__ float tile[32][33];
    int c0 = blockIdx.x * 32, r0 = blockIdx.y * 32;
    int tx = threadIdx.x, ty = threadIdx.y;
#pragma unroll
    for (int p = 0; p < 4; ++p)
        tile[ty + p * 8][tx] = src[(size_t)(r0 + ty + p * 8) * C + c0 + tx];
    __syncthreads();
#pragma unroll
    for (int p = 0; p < 4; ++p)
        dst[(size_t)(c0 + ty + p * 8) * R + r0 + tx] = f2bf(tile[tx][ty + p * 8]);
}

// ---------------- pack per-head qkv weights -> [2304,768] bf16 (n = sect*768+h*64+d) ----
__global__ __launch_bounds__(256) void k_packqkv(
    const float* __restrict__ wq1, const float* __restrict__ wk1, const float* __restrict__ wv1,
    const float* __restrict__ wq2, const float* __restrict__ wk2, const float* __restrict__ wv2,
    short* __restrict__ dst1, short* __restrict__ dst2) {
    __shared__ float tile[64][65];
    int z = blockIdx.y;                 // 0..71
    int set = z / 36, rem = z % 36, sect = rem / 12, h = rem % 12;
    const float* srcs[6] = {wq1, wk1, wv1, wq2, wk2, wv2};
    const float* src = srcs[set * 3 + sect] + (size_t)h * 768 * 64;
    short* dst = (set ? dst2 : dst1) + ((size_t)sect * 768 + h * 64) * 768;
    int k0 = blockIdx.x * 64;
    int t = threadIdx.x;
#pragma unroll
    for (int p = 0; p < 16; ++p) {
        int gid = t + p * 256;
        int r = gid >> 6, c = gid & 63;
        tile[r][c] = src[(size_t)(k0 + r) * 64 + c];
    }
    __syncthreads();
#pragma unroll
    for (int p = 0; p < 16; ++p) {
        int gid = t + p * 256;
        int d = gid >> 6, kk = gid & 63;
        dst[(size_t)d * 768 + k0 + kk] = f2bf(tile[kk][d]);
    }
}

__global__ void k_packbias(const float* __restrict__ bq1, const float* __restrict__ bk1,
                           const float* __restrict__ bv1, const float* __restrict__ bq2,
                           const float* __restrict__ bk2, const float* __restrict__ bv2,
                           float* __restrict__ d1, float* __restrict__ d2) {
    int tid = blockIdx.x * 256 + threadIdx.x;
    if (tid >= 4608) return;
    int set = tid / 2304, n = tid % 2304;
    int sect = n / 768, rem = n % 768;
    const float* srcs[6] = {bq1, bk1, bv1, bq2, bk2, bv2};
    float v = srcs[set * 3 + sect][rem];
    (set ? d2 : d1)[n] = v;
}

// ---------------- generic bf16 MFMA GEMM, 128xBN tile, 2x BK32 per barrier ----------------
// A [M,K] bf16 row-major; Bt [N,K] bf16 row-major (i.e. B transposed)
#define GM_FINAL 0
#define GM_PROJ  1
#define GM_GELU  2
#define GM_QKV   3
#define QKVSEC ((size_t)BATCH * NH * NTOK * HDIM)  // 6291456

template<int MODE, int BN>
__global__ __launch_bounds__(256) void k_gemm_mfma(
    const short* __restrict__ A, const short* __restrict__ Bt,
    const float* __restrict__ bias, const float* __restrict__ resid,
    const float* __restrict__ rscale, const float* __restrict__ alph,
    float* __restrict__ outF, short* __restrict__ outB, int M, int N, int K) {
    constexpr int NT = BN / 32;   // 16-col tiles per wave
    constexpr int BP = BN / 64;   // B staging passes per 32-chunk
    constexpr int STAGE = 2 * 128 * 32 + 2 * BN * 32;            // shorts
    constexpr int FINALS = (MODE == GM_FINAL) ? 64 * 132 * 2 : 0; // shorts (64 cols x 132-stride floats)
    constexpr int SMEM = STAGE > FINALS ? STAGE : FINALS;
    __shared__ short smem[SMEM];
    short* As = smem;
    short* Bs = smem + 2 * 128 * 32;
    int t = threadIdx.x;
    int w = t >> 6, lane = t & 63, l15 = lane & 15, quad = lane >> 4;
    int r0 = blockIdx.x * 128, n0 = blockIdx.y * BN;
    int wr = (w >> 1) * 64, wc = (w & 1) * (BN / 2);
    f32x4 acc[4][NT];
#pragma unroll
    for (int i = 0; i < 4; ++i)
#pragma unroll
        for (int j = 0; j < NT; ++j) acc[i][j] = (f32x4){0.f, 0.f, 0.f, 0.f};
    int sr = t >> 2, sc = (t & 3) * 8;
    const short* Ag = A + (size_t)(r0 + sr) * K + sc;
    const short* Bg = Bt + (size_t)(n0 + sr) * K + sc;
    short* AsW = As + w * 512;   // wave-uniform base: lane l -> + l*8 shorts (16 B)
    short* BsW = Bs + w * 512;
    for (int k0 = 0; k0 < K; k0 += 64) {
        __syncthreads();
#pragma unroll
        for (int c = 0; c < 2; ++c) {
#pragma unroll
            for (int p = 0; p < 2; ++p)
                async_copy16(Ag + k0 + c * 32 + (size_t)p * 64 * K,
                             AsW + c * 4096 + p * 2048);
#pragma unroll
            for (int p = 0; p < BP; ++p)
                async_copy16(Bg + k0 + c * 32 + (size_t)p * 64 * K,
                             BsW + c * (BN * 32) + p * 2048);
        }
        __syncthreads();   // drains vmcnt(0): DMA complete for all waves
#pragma unroll
        for (int c = 0; c < 2; ++c) {
            bf16x8 af[4], bf[NT];
#pragma unroll
            for (int i = 0; i < 4; ++i)
                af[i] = *(const bf16x8*)&As[c * 4096 + (wr + i * 16 + l15) * 32 + quad * 8];
#pragma unroll
            for (int j = 0; j < NT; ++j)
                bf[j] = *(const bf16x8*)&Bs[c * (BN * 32) + (wc + j * 16 + l15) * 32 + quad * 8];
#pragma unroll
            for (int i = 0; i < 4; ++i)
#pragma unroll
                for (int j = 0; j < NT; ++j)
                    acc[i][j] = __builtin_amdgcn_mfma_f32_16x16x32_bf16(af[i], bf[j], acc[i][j], 0, 0, 0);
        }
    }
    if (MODE == GM_FINAL) {
        // fused: val = rscale*val(+bias) + alph*resid; write transposed [B,C,N] via LDS
        __syncthreads();
        float* T = (float*)smem;
#pragma unroll
        for (int i = 0; i < 4; ++i)
#pragma unroll
            for (int j = 0; j < NT; ++j)
#pragma unroll
                for (int rr = 0; rr < 4; ++rr) {
                    int rl = wr + i * 16 + quad * 4 + rr;   // 0..127
                    int cl = wc + j * 16 + l15;             // 0..63
                    int row = r0 + rl, col = n0 + cl;
                    float val = acc[i][j][rr] + bias[col];
                    val = rscale[col] * val + alph[col] * resid[(size_t)row * N + col];
                    T[cl * 132 + rl] = val;
                }
        __syncthreads();
        int c = t >> 2, qo = (t & 3) * 32;
        int b = r0 >> 10, tokbase = r0 & 1023;
        float* obase = outF + ((size_t)(b * 768 + n0 + c)) * 1024 + tokbase + qo;
#pragma unroll
        for (int ii = 0; ii < 8; ++ii)
            *(float4*)&obase[ii * 4] = *(float4*)&T[c * 132 + qo + ii * 4];
        return;
    }
#pragma unroll
    for (int i = 0; i < 4; ++i)
#pragma unroll
        for (int j = 0; j < NT; ++j)
#pragma unroll
            for (int rr = 0; rr < 4; ++rr) {
                int row = r0 + wr + i * 16 + quad * 4 + rr;
                int col = n0 + wc + j * 16 + l15;
                float val = acc[i][j][rr] + bias[col];
                if (MODE == GM_PROJ) {
                    val += rscale[col] * resid[(size_t)row * N + col];
                    outF[(size_t)row * N + col] = val;
                } else if (MODE == GM_GELU) {
                    // tanh-form GELU via hw exp2/rcp: x*sigmoid(1.595769*(x+0.044715x^3))
                    float u = val * (1.0f + 0.044715f * val * val);
                    float zz = __builtin_amdgcn_rcpf(
                        1.0f + __builtin_amdgcn_exp2f(-2.3022082f * u));
                    outB[(size_t)row * N + col] = f2bf(val * zz);
                } else {  // GM_QKV: scatter into q/k/v [B,H,N,64]
                    int sect = col / 768, rem = col - sect * 768;
                    int hh = rem >> 6, d = rem & 63;
                    int bb = row >> 10, tok = row & 1023;
                    outB[(size_t)sect * QKVSEC +
                         (((size_t)bb * NH + hh) * NTOK + tok) * HDIM + d] = f2bf(val);
                }
            }
}

// ---------------- MFMA sigmoid attention ----------------
// per (b,h): O = sigmoid(QK^T/8) V ; q/k/v [B,H,N,64] bf16; O -> [B,N,C] bf16
__global__ __launch_bounds__(256) void k_attn_mfma(
    const short* __restrict__ q, const short* __restrict__ k,
    const short* __restrict__ v, short* __restrict__ o) {
    __shared__ short Ks[64][72];
    __shared__ short Vt[64][72];
    __shared__ short Ps[128][72];
    int b = blockIdx.z, h = blockIdx.y;
    int q0 = blockIdx.x * 128;
    int t = threadIdx.x;
    int w = t >> 6, lane = t & 63, l15 = lane & 15, quad = lane >> 4;
    size_t base = ((size_t)(b * NH + h)) * NTOK * HDIM;
    const short* qp = q + base;
    const short* kp = k + base;
    const short* vp = v + base;
    bf16x8 qf[2][2];
#pragma unroll
    for (int mt = 0; mt < 2; ++mt)
#pragma unroll
        for (int kc = 0; kc < 2; ++kc)
            qf[mt][kc] = *(const bf16x8*)&qp[(size_t)(q0 + w * 32 + mt * 16 + l15) * HDIM + kc * 32 + quad * 8];
    f32x4 oacc[2][4];
#pragma unroll
    for (int mt = 0; mt < 2; ++mt)
#pragma unroll
        for (int dt = 0; dt < 4; ++dt) oacc[mt][dt] = (f32x4){0.f, 0.f, 0.f, 0.f};
    for (int kt = 0; kt < 16; ++kt) {
        __syncthreads();
#pragma unroll
        for (int p = 0; p < 2; ++p) {
            int gid = t + p * 256;
            int r = gid >> 3, c8 = (gid & 7) * 8;
            *(bf16x8*)&Ks[r][c8] = *(const bf16x8*)&kp[(size_t)(kt * 64 + r) * HDIM + c8];
        }
#pragma unroll
        for (int p = 0; p < 2; ++p) {
            int tok = t & 63, d0 = (t >> 6) * 8 + p * 32;
            bf16x8 vv = *(const bf16x8*)&vp[(size_t)(kt * 64 + tok) * HDIM + d0];
#pragma unroll
            for (int j = 0; j < 8; ++j) Vt[d0 + j][tok] = vv[j];
        }
        __syncthreads();
        // S = Q K^T for this wave's 32 q-rows x 64 keys
        f32x4 sacc[2][4];
#pragma unroll
        for (int mt = 0; mt < 2; ++mt)
#pragma unroll
            for (int nt = 0; nt < 4; ++nt) sacc[mt][nt] = (f32x4){0.f, 0.f, 0.f, 0.f};
#pragma unroll
        for (int nt = 0; nt < 4; ++nt) {
            bf16x8 kf0 = *(const bf16x8*)&Ks[nt * 16 + l15][quad * 8];
            bf16x8 kf1 = *(const bf16x8*)&Ks[nt * 16 + l15][32 + quad * 8];
#pragma unroll
            for (int mt = 0; mt < 2; ++mt) {
                sacc[mt][nt] = __builtin_amdgcn_mfma_f32_16x16x32_bf16(qf[mt][0], kf0, sacc[mt][nt], 0, 0, 0);
                sacc[mt][nt] = __builtin_amdgcn_mfma_f32_16x16x32_bf16(qf[mt][1], kf1, sacc[mt][nt], 0, 0, 0);
            }
        }
        // sigmoid -> P (bf16, LDS round-trip to A-operand layout); rows wave-private
#pragma unroll
        for (int mt = 0; mt < 2; ++mt)
#pragma unroll
            for (int nt = 0; nt < 4; ++nt)
#pragma unroll
                for (int rr = 0; rr < 4; ++rr) {
                    float s = sacc[mt][nt][rr];
                    float z = __builtin_amdgcn_rcpf(
                        1.0f + __builtin_amdgcn_exp2f(s * -0.18033688011112042f));
                    Ps[w * 32 + mt * 16 + quad * 4 + rr][nt * 16 + l15] = f2bf(z);
                }
        __syncthreads();
        // O += P V
        bf16x8 vfr[2][4];
#pragma unroll
        for (int kc = 0; kc < 2; ++kc)
#pragma unroll
            for (int dt = 0; dt < 4; ++dt)
                vfr[kc][dt] = *(const bf16x8*)&Vt[dt * 16 + l15][kc * 32 + quad * 8];
#pragma unroll
        for (int mt = 0; mt < 2; ++mt)
#pragma unroll
            for (int kc = 0; kc < 2; ++kc) {
                bf16x8 pf = *(const bf16x8*)&Ps[w * 32 + mt * 16 + l15][kc * 32 + quad * 8];
#pragma unroll
                for (int dt = 0; dt < 4; ++dt)
                    oacc[mt][dt] = __builtin_amdgcn_mfma_f32_16x16x32_bf16(pf, vfr[kc][dt], oacc[mt][dt], 0, 0, 0);
            }
    }
#pragma unroll
    for (int mt = 0; mt < 2; ++mt)
#pragma unroll
        for (int dt = 0; dt < 4; ++dt)
#pragma unroll
            for (int rr = 0; rr < 4; ++rr) {
                int tok = q0 + w * 32 + mt * 16 + quad * 4 + rr;
                int c = h * 64 + dt * 16 + l15;
                o[((size_t)b * NTOK + tok) * CDIM + c] = f2bf(oacc[mt][dt][rr]);
            }
}

// ---------------- depthwise conv, register sliding window (fp32) ----------------
template<int K>
__global__ __launch_bounds__(256) void k_dwconv_t(
    const float* __restrict__ in, const float* __restrict__ w,
    const float* __restrict__ bias, float* __restrict__ out) {
    constexpr int PAD = K / 2;
    constexpr int KK = K * K;
    int t = threadIdx.x;
    int c = blockIdx.y * 64 + (t & 63);
    int j = blockIdx.x * 4 + (t >> 6);
    int b = blockIdx.z;
    float wr[KK];
#pragma unroll
    for (int qq = 0; qq < KK; ++qq) wr[qq] = w[(size_t)c * KK + qq];
    float bsv = bias[c];
    const float* base = in + (size_t)b * NTOK * CDIM + c;
    float win[K][K];
#pragma unroll
    for (int s = 1; s < K; ++s) {
        int ii = s - 1 - PAD;
#pragma unroll
        for (int qq = 0; qq < K; ++qq) {
            int jj = j - PAD + qq;
            win[s][qq] = (ii >= 0 && jj >= 0 && jj < 32)
                         ? base[(size_t)(ii * 32 + jj) * CDIM] : 0.0f;
        }
    }
#pragma unroll
    for (int i = 0; i < 32; ++i) {
#pragma unroll
        for (int r = 0; r < K - 1; ++r)
#pragma unroll
            for (int qq = 0; qq < K; ++qq) win[r][qq] = win[r + 1][qq];
        int ii = i + PAD;
#pragma unroll
        for (int qq = 0; qq < K; ++qq) {
            int jj = j - PAD + qq;
            win[K - 1][qq] = (ii < 32 && jj >= 0 && jj < 32)
                             ? base[(size_t)(ii * 32 + jj) * CDIM] : 0.0f;
        }
        float acc = bsv;
#pragma unroll
        for (int r = 0; r < K; ++r)
#pragma unroll
            for (int qq = 0; qq < K; ++qq)
                acc = fmaf(win[r][qq], wr[r * K + qq], acc);
        out[((size_t)b * NTOK + i * 32 + j) * CDIM + c] = acc;
    }
}

// ---------------- layernorm over C=768, nullable fp32/bf16 outputs ----------------
__global__ __launch_bounds__(256) void k_ln(
    const float* __restrict__ in, const float* __restrict__ g,
    const float* __restrict__ b, float* __restrict__ outF, short* __restrict__ outB) {
    int row = blockIdx.x;
    const float* xr = in + (size_t)row * CDIM;
    int t = threadIdx.x;
    float x0 = xr[t], x1 = xr[t + 256], x2 = xr[t + 512];
    float s = x0 + x1 + x2;
    float sq = x0 * x0 + x1 * x1 + x2 * x2;
#pragma unroll
    for (int off = 32; off > 0; off >>= 1) {
        s += __shfl_down(s, off);
        sq += __shfl_down(sq, off);
    }
    __shared__ float ws[4], wq2[4];
    int wid = t >> 6, lane = t & 63;
    if (lane == 0) { ws[wid] = s; wq2[wid] = sq; }
    __syncthreads();
    if (t == 0) {
        float S = ws[0] + ws[1] + ws[2] + ws[3];
        float Q = wq2[0] + wq2[1] + wq2[2] + wq2[3];
        float m = S * (1.0f / CDIM);
        float var = Q * (1.0f / CDIM) - m * m;
        ws[0] = m;
        wq2[0] = rsqrtf(var + 1e-5f);
    }
    __syncthreads();
    float m = ws[0], inv = wq2[0];
    float y0 = (x0 - m) * inv * g[t] + b[t];
    float y1 = (x1 - m) * inv * g[t + 256] + b[t + 256];
    float y2 = (x2 - m) * inv * g[t + 512] + b[t + 512];
    if (outF) {
        float* orow = outF + (size_t)row * CDIM;
        orow[t] = y0; orow[t + 256] = y1; orow[t + 512] = y2;
    }
    if (outB) {
        short* orow = outB + (size_t)row * CDIM;
        orow[t] = f2bf(y0); orow[t + 256] = f2bf(y1); orow[t + 512] = f2bf(y2);
    }
}

extern "C" void kernel_launch(void* const* d_in, const int* in_sizes, int n_in,
                              void* d_out, int out_size, void* d_ws, size_t ws_size,
                              hipStream_t stream) {
    const float* dec = (const float*)d_in[0];
    const float* wq1 = (const float*)d_in[1]; const float* bq1 = (const float*)d_in[2];
    const float* wk1 = (const float*)d_in[3]; const float* bk1 = (const float*)d_in[4];
    const float* wv1 = (const float*)d_in[5]; const float* bv1 = (const float*)d_in[6];
    const float* wo1 = (const float*)d_in[7]; const float* bo1 = (const float*)d_in[8];
    const float* wq2 = (const float*)d_in[9]; const float* bq2 = (const float*)d_in[10];
    const float* wk2 = (const float*)d_in[11]; const float* bk2 = (const float*)d_in[12];
    const float* wv2 = (const float*)d_in[13]; const float* bv2 = (const float*)d_in[14];
    const float* wo2 = (const float*)d_in[15]; const float* bo2 = (const float*)d_in[16];
    const float* alphas1 = (const float*)d_in[17];
    const float* alphas2 = (const float*)d_in[18];
    const float* peg_w = (const float*)d_in[19]; const float* peg_b = (const float*)d_in[20];
    const float* ln1_g = (const float*)d_in[21]; const float* ln1_b = (const float*)d_in[22];
    const float* ln2_g = (const float*)d_in[23]; const float* ln2_b = (const float*)d_in[24];
    const float* cn_dw_w = (const float*)d_in[25]; const float* cn_dw_b = (const float*)d_in[26];
    const float* cn_ln_g = (const float*)d_in[27]; const float* cn_ln_b = (const float*)d_in[28];
    const float* cn_w1 = (const float*)d_in[29]; const float* cn_b1 = (const float*)d_in[30];
    const float* cn_w2 = (const float*)d_in[31]; const float* cn_b2 = (const float*)d_in[32];
    const float* cn_scale = (const float*)d_in[33]; const float* cn_alphas = (const float*)d_in[34];
    float* out = (float*)d_out;

    const size_t S = (size_t)BATCH * NTOK * CDIM;  // 6291456
    float* A0 = (float*)d_ws;
    float* A1 = A0 + S;
    short* Xb  = (short*)(A1 + S);
    short* QKV = Xb + S;            // 3*S bf16 (q | k | v)
    short* Ob  = QKV + 3 * S;
    short* Hb  = Ob + S;            // 2*S bf16
    short* Wqkv1 = Hb + 2 * S;
    short* Wqkv2 = Wqkv1 + 2304 * 768;
    short* WoT1  = Wqkv2 + 2304 * 768;
    short* WoT2  = WoT1 + 768 * 768;
    short* W1T   = WoT2 + 768 * 768;
    short* W2T   = W1T + (size_t)3072 * 768;
    float* bqkv1 = (float*)(W2T + (size_t)768 * 3072);
    float* bqkv2 = bqkv1 + 2304;
    // MLP-time alias (QKV/Ob/Hb regions dead by then):
    short* Hfull = QKV + 2 * S;     // 8192x3072 bf16 = 4S shorts

    dim3 tb(32, 8);
    dim3 dwgrid(8, 12, 8);

    // ---- weight prep (per-launch) ----
    k_packqkv<<<dim3(12, 72), 256, 0, stream>>>(wq1, wk1, wv1, wq2, wk2, wv2, Wqkv1, Wqkv2);
    k_wtrans<<<dim3(24, 24), tb, 0, stream>>>(wo1, WoT1, 768, 768);
    k_wtrans<<<dim3(24, 24), tb, 0, stream>>>(wo2, WoT2, 768, 768);
    k_wtrans<<<dim3(96, 24), tb, 0, stream>>>(cn_w1, W1T, 768, 3072);
    k_wtrans<<<dim3(24, 96), tb, 0, stream>>>(cn_w2, W2T, 3072, 768);
    k_packbias<<<18, 256, 0, stream>>>(bq1, bk1, bv1, bq2, bk2, bv2, bqkv1, bqkv2);

    // ---- x = transpose(decoder), fp32 + bf16 ----
    k_transpose_in<<<dim3(32, 24, 8), tb, 0, stream>>>(dec, A0, Xb);

    // ---- block 1 ----
    k_gemm_mfma<GM_QKV, 256><<<dim3(64, 9), 256, 0, stream>>>(
        Xb, Wqkv1, bqkv1, nullptr, nullptr, nullptr, nullptr, QKV, 8192, 2304, 768);
    k_attn_mfma<<<dim3(8, 12, 8), 256, 0, stream>>>(QKV, QKV + S, QKV + 2 * S, Ob);
    k_gemm_mfma<GM_PROJ, 64><<<dim3(64, 12), 256, 0, stream>>>(
        Ob, WoT1, bo1, A0, alphas1, nullptr, A1, nullptr, 8192, 768, 768);
    k_dwconv_t<3><<<dwgrid, 256, 0, stream>>>(A1, peg_w, peg_b, A0);
    k_ln<<<8192, 256, 0, stream>>>(A0, ln1_g, ln1_b, A1, Xb);

    // ---- block 2 ----
    k_gemm_mfma<GM_QKV, 256><<<dim3(64, 9), 256, 0, stream>>>(
        Xb, Wqkv2, bqkv2, nullptr, nullptr, nullptr, nullptr, QKV, 8192, 2304, 768);
    k_attn_mfma<<<dim3(8, 12, 8), 256, 0, stream>>>(QKV, QKV + S, QKV + 2 * S, Ob);
    k_gemm_mfma<GM_PROJ, 64><<<dim3(64, 12), 256, 0, stream>>>(
        Ob, WoT2, bo2, A1, alphas2, nullptr, A0, nullptr, 8192, 768, 768);
    k_ln<<<8192, 256, 0, stream>>>(A0, ln2_g, ln2_b, A1, nullptr);  // A1 = xln2 (kept)

    // ---- CNBlock head ----
    k_dwconv_t<7><<<dwgrid, 256, 0, stream>>>(A1, cn_dw_w, cn_dw_b, A0);
    k_ln<<<8192, 256, 0, stream>>>(A0, cn_ln_g, cn_ln_b, nullptr, Xb);
    // MLP, full M=8192; down-proj fused with layer-scale residual + output transpose
    k_gemm_mfma<GM_GELU, 256><<<dim3(64, 12), 256, 0, stream>>>(
        Xb, W1T, cn_b1, nullptr, nullptr, nullptr, nullptr, Hfull, 8192, 3072, 768);
    k_gemm_mfma<GM_FINAL, 64><<<dim3(64, 12), 256, 0, stream>>>(
        Hfull, W2T, cn_b2, A1, cn_scale, cn_alphas, out, nullptr, 8192, 768, 3072);
}

// Round 9
// 651.058 us; speedup vs baseline: 1.1284x; 1.1284x over previous
//
#include <hip/hip_runtime.h>
#include <math.h>

#define BATCH 8
#define CDIM 768
#define NTOK 1024
#define NH 12
#define HDIM 64

typedef __attribute__((ext_vector_type(8))) short bf16x8;
typedef __attribute__((ext_vector_type(4))) float f32x4;

__device__ inline short f2bf(float f) {
    union { float f; unsigned u; } v; v.f = f;
    unsigned r = (v.u + 0x7FFF + ((v.u >> 16) & 1)) >> 16;
    return (short)r;
}

// async global->LDS DMA, 16 B per lane; lptr must be the WAVE-uniform base,
// lane l writes lptr + l*16 bytes (m97 pattern).
__device__ inline void async_copy16(const short* g, short* l) {
    __builtin_amdgcn_global_load_lds(
        (const __attribute__((address_space(1))) void*)g,
        (__attribute__((address_space(3))) void*)l, 16, 0, 0);
}

// ---------------- transpose [B,C,N] -> [B,N,C], fp32 + bf16 mirror ----------------
__global__ void k_transpose_in(const float* __restrict__ dec, float* __restrict__ x,
                               short* __restrict__ xb) {
    __shared__ float tile[32][33];
    int b = blockIdx.z;
    int n0 = blockIdx.x * 32;
    int c0 = blockIdx.y * 32;
    int tx = threadIdx.x, ty = threadIdx.y;
#pragma unroll
    for (int r = 0; r < 4; ++r) {
        int c = c0 + ty + r * 8;
        tile[ty + r * 8][tx] = dec[((size_t)b * CDIM + c) * NTOK + n0 + tx];
    }
    __syncthreads();
#pragma unroll
    for (int r = 0; r < 4; ++r) {
        int n = n0 + ty + r * 8;
        float val = tile[tx][ty + r * 8];
        size_t idx = ((size_t)b * NTOK + n) * CDIM + c0 + tx;
        x[idx] = val;
        xb[idx] = f2bf(val);
    }
}

// ---------------- weight transpose fp32 [R,C] -> bf16 [C,R] ----------------
__global__ void k_wtrans(const float* __restrict__ src, short* __restrict__ dst,
                         int R, int C) {
    __shared__ float tile[32][33];
    int c0 = blockIdx.x * 32, r0 = blockIdx.y * 32;
    int tx = threadIdx.x, ty = threadIdx.y;
#pragma unroll
    for (int p = 0; p < 4; ++p)
        tile[ty + p * 8][tx] = src[(size_t)(r0 + ty + p * 8) * C + c0 + tx];
    __syncthreads();
#pragma unroll
    for (int p = 0; p < 4; ++p)
        dst[(size_t)(c0 + ty + p * 8) * R + r0 + tx] = f2bf(tile[tx][ty + p * 8]);
}

// ---------------- pack per-head qkv weights -> [2304,768] bf16 (n = sect*768+h*64+d) ----
__global__ __launch_bounds__(256) void k_packqkv(
    const float* __restrict__ wq1, const float* __restrict__ wk1, const float* __restrict__ wv1,
    const float* __restrict__ wq2, const float* __restrict__ wk2, const float* __restrict__ wv2,
    short* __restrict__ dst1, short* __restrict__ dst2) {
    __shared__ float tile[64][65];
    int z = blockIdx.y;                 // 0..71
    int set = z / 36, rem = z % 36, sect = rem / 12, h = rem % 12;
    const float* srcs[6] = {wq1, wk1, wv1, wq2, wk2, wv2};
    const float* src = srcs[set * 3 + sect] + (size_t)h * 768 * 64;
    short* dst = (set ? dst2 : dst1) + ((size_t)sect * 768 + h * 64) * 768;
    int k0 = blockIdx.x * 64;
    int t = threadIdx.x;
#pragma unroll
    for (int p = 0; p < 16; ++p) {
        int gid = t + p * 256;
        int r = gid >> 6, c = gid & 63;
        tile[r][c] = src[(size_t)(k0 + r) * 64 + c];
    }
    __syncthreads();
#pragma unroll
    for (int p = 0; p < 16; ++p) {
        int gid = t + p * 256;
        int d = gid >> 6, kk = gid & 63;
        dst[(size_t)d * 768 + k0 + kk] = f2bf(tile[kk][d]);
    }
}

__global__ void k_packbias(const float* __restrict__ bq1, const float* __restrict__ bk1,
                           const float* __restrict__ bv1, const float* __restrict__ bq2,
                           const float* __restrict__ bk2, const float* __restrict__ bv2,
                           float* __restrict__ d1, float* __restrict__ d2) {
    int tid = blockIdx.x * 256 + threadIdx.x;
    if (tid >= 4608) return;
    int set = tid / 2304, n = tid % 2304;
    int sect = n / 768, rem = n % 768;
    const float* srcs[6] = {bq1, bk1, bv1, bq2, bk2, bv2};
    float v = srcs[set * 3 + sect][rem];
    (set ? d2 : d1)[n] = v;
}

// ---------------- generic bf16 MFMA GEMM, 128xBN tile, 2x BK32 per barrier ----------------
// A [M,K] bf16 row-major; Bt [N,K] bf16 row-major (i.e. B transposed)
// BN=128 for wide-N (occupancy sweet spot, r7/r8 A-B tested), BN=64 for N=768.
#define GM_FINAL 0
#define GM_PROJ  1
#define GM_GELU  2
#define GM_QKV   3
#define QKVSEC ((size_t)BATCH * NH * NTOK * HDIM)  // 6291456

template<int MODE, int BN>
__global__ __launch_bounds__(256) void k_gemm_mfma(
    const short* __restrict__ A, const short* __restrict__ Bt,
    const float* __restrict__ bias, const float* __restrict__ resid,
    const float* __restrict__ rscale, const float* __restrict__ alph,
    float* __restrict__ outF, short* __restrict__ outB, int M, int N, int K) {
    constexpr int NT = BN / 32;   // 16-col tiles per wave
    constexpr int BP = BN / 64;   // B staging passes per 32-chunk
    constexpr int STAGE = 2 * 128 * 32 + 2 * BN * 32;            // shorts
    constexpr int FINALS = (MODE == GM_FINAL) ? 64 * 132 * 2 : 0; // shorts (64 cols x 132-stride floats)
    constexpr int SMEM = STAGE > FINALS ? STAGE : FINALS;
    __shared__ short smem[SMEM];
    short* As = smem;
    short* Bs = smem + 2 * 128 * 32;
    int t = threadIdx.x;
    int w = t >> 6, lane = t & 63, l15 = lane & 15, quad = lane >> 4;
    int r0 = blockIdx.x * 128, n0 = blockIdx.y * BN;
    int wr = (w >> 1) * 64, wc = (w & 1) * (BN / 2);
    f32x4 acc[4][NT];
#pragma unroll
    for (int i = 0; i < 4; ++i)
#pragma unroll
        for (int j = 0; j < NT; ++j) acc[i][j] = (f32x4){0.f, 0.f, 0.f, 0.f};
    int sr = t >> 2, sc = (t & 3) * 8;
    const short* Ag = A + (size_t)(r0 + sr) * K + sc;
    const short* Bg = Bt + (size_t)(n0 + sr) * K + sc;
    short* AsW = As + w * 512;   // wave-uniform base: lane l -> + l*8 shorts (16 B)
    short* BsW = Bs + w * 512;
    for (int k0 = 0; k0 < K; k0 += 64) {
        __syncthreads();
#pragma unroll
        for (int c = 0; c < 2; ++c) {
#pragma unroll
            for (int p = 0; p < 2; ++p)
                async_copy16(Ag + k0 + c * 32 + (size_t)p * 64 * K,
                             AsW + c * 4096 + p * 2048);
#pragma unroll
            for (int p = 0; p < BP; ++p)
                async_copy16(Bg + k0 + c * 32 + (size_t)p * 64 * K,
                             BsW + c * (BN * 32) + p * 2048);
        }
        __syncthreads();   // drains vmcnt(0): DMA complete for all waves
#pragma unroll
        for (int c = 0; c < 2; ++c) {
            bf16x8 af[4], bf[NT];
#pragma unroll
            for (int i = 0; i < 4; ++i)
                af[i] = *(const bf16x8*)&As[c * 4096 + (wr + i * 16 + l15) * 32 + quad * 8];
#pragma unroll
            for (int j = 0; j < NT; ++j)
                bf[j] = *(const bf16x8*)&Bs[c * (BN * 32) + (wc + j * 16 + l15) * 32 + quad * 8];
#pragma unroll
            for (int i = 0; i < 4; ++i)
#pragma unroll
                for (int j = 0; j < NT; ++j)
                    acc[i][j] = __builtin_amdgcn_mfma_f32_16x16x32_bf16(af[i], bf[j], acc[i][j], 0, 0, 0);
        }
    }
    if (MODE == GM_FINAL) {
        // fused: val = rscale*val(+bias) + alph*resid; write transposed [B,C,N] via LDS
        __syncthreads();
        float* T = (float*)smem;
#pragma unroll
        for (int i = 0; i < 4; ++i)
#pragma unroll
            for (int j = 0; j < NT; ++j)
#pragma unroll
                for (int rr = 0; rr < 4; ++rr) {
                    int rl = wr + i * 16 + quad * 4 + rr;   // 0..127
                    int cl = wc + j * 16 + l15;             // 0..63
                    int row = r0 + rl, col = n0 + cl;
                    float val = acc[i][j][rr] + bias[col];
                    val = rscale[col] * val + alph[col] * resid[(size_t)row * N + col];
                    T[cl * 132 + rl] = val;
                }
        __syncthreads();
        int c = t >> 2, qo = (t & 3) * 32;
        int b = r0 >> 10, tokbase = r0 & 1023;
        float* obase = outF + ((size_t)(b * 768 + n0 + c)) * 1024 + tokbase + qo;
#pragma unroll
        for (int ii = 0; ii < 8; ++ii)
            *(float4*)&obase[ii * 4] = *(float4*)&T[c * 132 + qo + ii * 4];
        return;
    }
#pragma unroll
    for (int i = 0; i < 4; ++i)
#pragma unroll
        for (int j = 0; j < NT; ++j)
#pragma unroll
            for (int rr = 0; rr < 4; ++rr) {
                int row = r0 + wr + i * 16 + quad * 4 + rr;
                int col = n0 + wc + j * 16 + l15;
                float val = acc[i][j][rr] + bias[col];
                if (MODE == GM_PROJ) {
                    val += rscale[col] * resid[(size_t)row * N + col];
                    outF[(size_t)row * N + col] = val;
                } else if (MODE == GM_GELU) {
                    // tanh-form GELU via hw exp2/rcp: x*sigmoid(1.595769*(x+0.044715x^3))
                    float u = val * (1.0f + 0.044715f * val * val);
                    float zz = __builtin_amdgcn_rcpf(
                        1.0f + __builtin_amdgcn_exp2f(-2.3022082f * u));
                    outB[(size_t)row * N + col] = f2bf(val * zz);
                } else {  // GM_QKV: scatter into q/k/v [B,H,N,64]
                    int sect = col / 768, rem = col - sect * 768;
                    int hh = rem >> 6, d = rem & 63;
                    int bb = row >> 10, tok = row & 1023;
                    outB[(size_t)sect * QKVSEC +
                         (((size_t)bb * NH + hh) * NTOK + tok) * HDIM + d] = f2bf(val);
                }
            }
}

// ---------------- MFMA sigmoid attention ----------------
// per (b,h): O = sigmoid(QK^T/8) V ; q/k/v [B,H,N,64] bf16; O -> [B,N,C] bf16
__global__ __launch_bounds__(256) void k_attn_mfma(
    const short* __restrict__ q, const short* __restrict__ k,
    const short* __restrict__ v, short* __restrict__ o) {
    __shared__ short Ks[64][72];
    __shared__ short Vt[64][72];
    __shared__ short Ps[128][72];
    int b = blockIdx.z, h = blockIdx.y;
    int q0 = blockIdx.x * 128;
    int t = threadIdx.x;
    int w = t >> 6, lane = t & 63, l15 = lane & 15, quad = lane >> 4;
    size_t base = ((size_t)(b * NH + h)) * NTOK * HDIM;
    const short* qp = q + base;
    const short* kp = k + base;
    const short* vp = v + base;
    bf16x8 qf[2][2];
#pragma unroll
    for (int mt = 0; mt < 2; ++mt)
#pragma unroll
        for (int kc = 0; kc < 2; ++kc)
            qf[mt][kc] = *(const bf16x8*)&qp[(size_t)(q0 + w * 32 + mt * 16 + l15) * HDIM + kc * 32 + quad * 8];
    f32x4 oacc[2][4];
#pragma unroll
    for (int mt = 0; mt < 2; ++mt)
#pragma unroll
        for (int dt = 0; dt < 4; ++dt) oacc[mt][dt] = (f32x4){0.f, 0.f, 0.f, 0.f};
    for (int kt = 0; kt < 16; ++kt) {
        __syncthreads();
#pragma unroll
        for (int p = 0; p < 2; ++p) {
            int gid = t + p * 256;
            int r = gid >> 3, c8 = (gid & 7) * 8;
            *(bf16x8*)&Ks[r][c8] = *(const bf16x8*)&kp[(size_t)(kt * 64 + r) * HDIM + c8];
        }
#pragma unroll
        for (int p = 0; p < 2; ++p) {
            int tok = t & 63, d0 = (t >> 6) * 8 + p * 32;
            bf16x8 vv = *(const bf16x8*)&vp[(size_t)(kt * 64 + tok) * HDIM + d0];
#pragma unroll
            for (int j = 0; j < 8; ++j) Vt[d0 + j][tok] = vv[j];
        }
        __syncthreads();
        // S = Q K^T for this wave's 32 q-rows x 64 keys
        f32x4 sacc[2][4];
#pragma unroll
        for (int mt = 0; mt < 2; ++mt)
#pragma unroll
            for (int nt = 0; nt < 4; ++nt) sacc[mt][nt] = (f32x4){0.f, 0.f, 0.f, 0.f};
#pragma unroll
        for (int nt = 0; nt < 4; ++nt) {
            bf16x8 kf0 = *(const bf16x8*)&Ks[nt * 16 + l15][quad * 8];
            bf16x8 kf1 = *(const bf16x8*)&Ks[nt * 16 + l15][32 + quad * 8];
#pragma unroll
            for (int mt = 0; mt < 2; ++mt) {
                sacc[mt][nt] = __builtin_amdgcn_mfma_f32_16x16x32_bf16(qf[mt][0], kf0, sacc[mt][nt], 0, 0, 0);
                sacc[mt][nt] = __builtin_amdgcn_mfma_f32_16x16x32_bf16(qf[mt][1], kf1, sacc[mt][nt], 0, 0, 0);
            }
        }
        // sigmoid -> P (bf16, LDS round-trip to A-operand layout); rows wave-private
#pragma unroll
        for (int mt = 0; mt < 2; ++mt)
#pragma unroll
            for (int nt = 0; nt < 4; ++nt)
#pragma unroll
                for (int rr = 0; rr < 4; ++rr) {
                    float s = sacc[mt][nt][rr];
                    float z = __builtin_amdgcn_rcpf(
                        1.0f + __builtin_amdgcn_exp2f(s * -0.18033688011112042f));
                    Ps[w * 32 + mt * 16 + quad * 4 + rr][nt * 16 + l15] = f2bf(z);
                }
        __syncthreads();
        // O += P V
        bf16x8 vfr[2][4];
#pragma unroll
        for (int kc = 0; kc < 2; ++kc)
#pragma unroll
            for (int dt = 0; dt < 4; ++dt)
                vfr[kc][dt] = *(const bf16x8*)&Vt[dt * 16 + l15][kc * 32 + quad * 8];
#pragma unroll
        for (int mt = 0; mt < 2; ++mt)
#pragma unroll
            for (int kc = 0; kc < 2; ++kc) {
                bf16x8 pf = *(const bf16x8*)&Ps[w * 32 + mt * 16 + l15][kc * 32 + quad * 8];
#pragma unroll
                for (int dt = 0; dt < 4; ++dt)
                    oacc[mt][dt] = __builtin_amdgcn_mfma_f32_16x16x32_bf16(pf, vfr[kc][dt], oacc[mt][dt], 0, 0, 0);
            }
    }
#pragma unroll
    for (int mt = 0; mt < 2; ++mt)
#pragma unroll
        for (int dt = 0; dt < 4; ++dt)
#pragma unroll
            for (int rr = 0; rr < 4; ++rr) {
                int tok = q0 + w * 32 + mt * 16 + quad * 4 + rr;
                int c = h * 64 + dt * 16 + l15;
                o[((size_t)b * NTOK + tok) * CDIM + c] = f2bf(oacc[mt][dt][rr]);
            }
}

// ---------------- depthwise conv, register sliding window (fp32) ----------------
template<int K>
__global__ __launch_bounds__(256) void k_dwconv_t(
    const float* __restrict__ in, const float* __restrict__ w,
    const float* __restrict__ bias, float* __restrict__ out) {
    constexpr int PAD = K / 2;
    constexpr int KK = K * K;
    int t = threadIdx.x;
    int c = blockIdx.y * 64 + (t & 63);
    int j = blockIdx.x * 4 + (t >> 6);
    int b = blockIdx.z;
    float wr[KK];
#pragma unroll
    for (int qq = 0; qq < KK; ++qq) wr[qq] = w[(size_t)c * KK + qq];
    float bsv = bias[c];
    const float* base = in + (size_t)b * NTOK * CDIM + c;
    float win[K][K];
#pragma unroll
    for (int s = 1; s < K; ++s) {
        int ii = s - 1 - PAD;
#pragma unroll
        for (int qq = 0; qq < K; ++qq) {
            int jj = j - PAD + qq;
            win[s][qq] = (ii >= 0 && jj >= 0 && jj < 32)
                         ? base[(size_t)(ii * 32 + jj) * CDIM] : 0.0f;
        }
    }
#pragma unroll
    for (int i = 0; i < 32; ++i) {
#pragma unroll
        for (int r = 0; r < K - 1; ++r)
#pragma unroll
            for (int qq = 0; qq < K; ++qq) win[r][qq] = win[r + 1][qq];
        int ii = i + PAD;
#pragma unroll
        for (int qq = 0; qq < K; ++qq) {
            int jj = j - PAD + qq;
            win[K - 1][qq] = (ii < 32 && jj >= 0 && jj < 32)
                             ? base[(size_t)(ii * 32 + jj) * CDIM] : 0.0f;
        }
        float acc = bsv;
#pragma unroll
        for (int r = 0; r < K; ++r)
#pragma unroll
            for (int qq = 0; qq < K; ++qq)
                acc = fmaf(win[r][qq], wr[r * K + qq], acc);
        out[((size_t)b * NTOK + i * 32 + j) * CDIM + c] = acc;
    }
}

// ---------------- layernorm over C=768, nullable fp32/bf16 outputs ----------------
__global__ __launch_bounds__(256) void k_ln(
    const float* __restrict__ in, const float* __restrict__ g,
    const float* __restrict__ b, float* __restrict__ outF, short* __restrict__ outB) {
    int row = blockIdx.x;
    const float* xr = in + (size_t)row * CDIM;
    int t = threadIdx.x;
    float x0 = xr[t], x1 = xr[t + 256], x2 = xr[t + 512];
    float s = x0 + x1 + x2;
    float sq = x0 * x0 + x1 * x1 + x2 * x2;
#pragma unroll
    for (int off = 32; off > 0; off >>= 1) {
        s += __shfl_down(s, off);
        sq += __shfl_down(sq, off);
    }
    __shared__ float ws[4], wq2[4];
    int wid = t >> 6, lane = t & 63;
    if (lane == 0) { ws[wid] = s; wq2[wid] = sq; }
    __syncthreads();
    if (t == 0) {
        float S = ws[0] + ws[1] + ws[2] + ws[3];
        float Q = wq2[0] + wq2[1] + wq2[2] + wq2[3];
        float m = S * (1.0f / CDIM);
        float var = Q * (1.0f / CDIM) - m * m;
        ws[0] = m;
        wq2[0] = rsqrtf(var + 1e-5f);
    }
    __syncthreads();
    float m = ws[0], inv = wq2[0];
    float y0 = (x0 - m) * inv * g[t] + b[t];
    float y1 = (x1 - m) * inv * g[t + 256] + b[t + 256];
    float y2 = (x2 - m) * inv * g[t + 512] + b[t + 512];
    if (outF) {
        float* orow = outF + (size_t)row * CDIM;
        orow[t] = y0; orow[t + 256] = y1; orow[t + 512] = y2;
    }
    if (outB) {
        short* orow = outB + (size_t)row * CDIM;
        orow[t] = f2bf(y0); orow[t + 256] = f2bf(y1); orow[t + 512] = f2bf(y2);
    }
}

extern "C" void kernel_launch(void* const* d_in, const int* in_sizes, int n_in,
                              void* d_out, int out_size, void* d_ws, size_t ws_size,
                              hipStream_t stream) {
    const float* dec = (const float*)d_in[0];
    const float* wq1 = (const float*)d_in[1]; const float* bq1 = (const float*)d_in[2];
    const float* wk1 = (const float*)d_in[3]; const float* bk1 = (const float*)d_in[4];
    const float* wv1 = (const float*)d_in[5]; const float* bv1 = (const float*)d_in[6];
    const float* wo1 = (const float*)d_in[7]; const float* bo1 = (const float*)d_in[8];
    const float* wq2 = (const float*)d_in[9]; const float* bq2 = (const float*)d_in[10];
    const float* wk2 = (const float*)d_in[11]; const float* bk2 = (const float*)d_in[12];
    const float* wv2 = (const float*)d_in[13]; const float* bv2 = (const float*)d_in[14];
    const float* wo2 = (const float*)d_in[15]; const float* bo2 = (const float*)d_in[16];
    const float* alphas1 = (const float*)d_in[17];
    const float* alphas2 = (const float*)d_in[18];
    const float* peg_w = (const float*)d_in[19]; const float* peg_b = (const float*)d_in[20];
    const float* ln1_g = (const float*)d_in[21]; const float* ln1_b = (const float*)d_in[22];
    const float* ln2_g = (const float*)d_in[23]; const float* ln2_b = (const float*)d_in[24];
    const float* cn_dw_w = (const float*)d_in[25]; const float* cn_dw_b = (const float*)d_in[26];
    const float* cn_ln_g = (const float*)d_in[27]; const float* cn_ln_b = (const float*)d_in[28];
    const float* cn_w1 = (const float*)d_in[29]; const float* cn_b1 = (const float*)d_in[30];
    const float* cn_w2 = (const float*)d_in[31]; const float* cn_b2 = (const float*)d_in[32];
    const float* cn_scale = (const float*)d_in[33]; const float* cn_alphas = (const float*)d_in[34];
    float* out = (float*)d_out;

    const size_t S = (size_t)BATCH * NTOK * CDIM;  // 6291456
    float* A0 = (float*)d_ws;
    float* A1 = A0 + S;
    short* Xb  = (short*)(A1 + S);
    short* QKV = Xb + S;            // 3*S bf16 (q | k | v)
    short* Ob  = QKV + 3 * S;
    short* Hb  = Ob + S;            // 2*S bf16
    short* Wqkv1 = Hb + 2 * S;
    short* Wqkv2 = Wqkv1 + 2304 * 768;
    short* WoT1  = Wqkv2 + 2304 * 768;
    short* WoT2  = WoT1 + 768 * 768;
    short* W1T   = WoT2 + 768 * 768;
    short* W2T   = W1T + (size_t)3072 * 768;
    float* bqkv1 = (float*)(W2T + (size_t)768 * 3072);
    float* bqkv2 = bqkv1 + 2304;
    // MLP-time alias (QKV/Ob/Hb regions dead by then):
    short* Hfull = QKV + 2 * S;     // 8192x3072 bf16 = 4S shorts

    dim3 tb(32, 8);
    dim3 dwgrid(8, 12, 8);

    // ---- weight prep (per-launch) ----
    k_packqkv<<<dim3(12, 72), 256, 0, stream>>>(wq1, wk1, wv1, wq2, wk2, wv2, Wqkv1, Wqkv2);
    k_wtrans<<<dim3(24, 24), tb, 0, stream>>>(wo1, WoT1, 768, 768);
    k_wtrans<<<dim3(24, 24), tb, 0, stream>>>(wo2, WoT2, 768, 768);
    k_wtrans<<<dim3(96, 24), tb, 0, stream>>>(cn_w1, W1T, 768, 3072);
    k_wtrans<<<dim3(24, 96), tb, 0, stream>>>(cn_w2, W2T, 3072, 768);
    k_packbias<<<18, 256, 0, stream>>>(bq1, bk1, bv1, bq2, bk2, bv2, bqkv1, bqkv2);

    // ---- x = transpose(decoder), fp32 + bf16 ----
    k_transpose_in<<<dim3(32, 24, 8), tb, 0, stream>>>(dec, A0, Xb);

    // ---- block 1 ----
    k_gemm_mfma<GM_QKV, 128><<<dim3(64, 18), 256, 0, stream>>>(
        Xb, Wqkv1, bqkv1, nullptr, nullptr, nullptr, nullptr, QKV, 8192, 2304, 768);
    k_attn_mfma<<<dim3(8, 12, 8), 256, 0, stream>>>(QKV, QKV + S, QKV + 2 * S, Ob);
    k_gemm_mfma<GM_PROJ, 64><<<dim3(64, 12), 256, 0, stream>>>(
        Ob, WoT1, bo1, A0, alphas1, nullptr, A1, nullptr, 8192, 768, 768);
    k_dwconv_t<3><<<dwgrid, 256, 0, stream>>>(A1, peg_w, peg_b, A0);
    k_ln<<<8192, 256, 0, stream>>>(A0, ln1_g, ln1_b, A1, Xb);

    // ---- block 2 ----
    k_gemm_mfma<GM_QKV, 128><<<dim3(64, 18), 256, 0, stream>>>(
        Xb, Wqkv2, bqkv2, nullptr, nullptr, nullptr, nullptr, QKV, 8192, 2304, 768);
    k_attn_mfma<<<dim3(8, 12, 8), 256, 0, stream>>>(QKV, QKV + S, QKV + 2 * S, Ob);
    k_gemm_mfma<GM_PROJ, 64><<<dim3(64, 12), 256, 0, stream>>>(
        Ob, WoT2, bo2, A1, alphas2, nullptr, A0, nullptr, 8192, 768, 768);
    k_ln<<<8192, 256, 0, stream>>>(A0, ln2_g, ln2_b, A1, nullptr);  // A1 = xln2 (kept)

    // ---- CNBlock head ----
    k_dwconv_t<7><<<dwgrid, 256, 0, stream>>>(A1, cn_dw_w, cn_dw_b, A0);
    k_ln<<<8192, 256, 0, stream>>>(A0, cn_ln_g, cn_ln_b, nullptr, Xb);
    // MLP, full M=8192; down-proj fused with layer-scale residual + output transpose
    k_gemm_mfma<GM_GELU, 128><<<dim3(64, 24), 256, 0, stream>>>(
        Xb, W1T, cn_b1, nullptr, nullptr, nullptr, nullptr, Hfull, 8192, 3072, 768);
    k_gemm_mfma<GM_FINAL, 64><<<dim3(64, 12), 256, 0, stream>>>(
        Hfull, W2T, cn_b2, A1, cn_scale, cn_alphas, out, nullptr, 8192, 768, 3072);
}

// Round 10
// 622.367 us; speedup vs baseline: 1.1804x; 1.0461x over previous
//
#include <hip/hip_runtime.h>
#include <math.h>

#define BATCH 8
#define CDIM 768
#define NTOK 1024
#define NH 12
#define HDIM 64

typedef __attribute__((ext_vector_type(8))) short bf16x8;
typedef __attribute__((ext_vector_type(4))) float f32x4;

__device__ inline short f2bf(float f) {
    union { float f; unsigned u; } v; v.f = f;
    unsigned r = (v.u + 0x7FFF + ((v.u >> 16) & 1)) >> 16;
    return (short)r;
}

// async global->LDS DMA, 16 B per lane; lptr must be the WAVE-uniform base,
// lane l writes lptr + l*16 bytes (m97 pattern).
__device__ inline void async_copy16(const short* g, short* l) {
    __builtin_amdgcn_global_load_lds(
        (const __attribute__((address_space(1))) void*)g,
        (__attribute__((address_space(3))) void*)l, 16, 0, 0);
}

// ---------------- transpose [B,C,N] -> [B,N,C], fp32 + bf16 mirror ----------------
__global__ void k_transpose_in(const float* __restrict__ dec, float* __restrict__ x,
                               short* __restrict__ xb) {
    __shared__ float tile[32][33];
    int b = blockIdx.z;
    int n0 = blockIdx.x * 32;
    int c0 = blockIdx.y * 32;
    int tx = threadIdx.x, ty = threadIdx.y;
#pragma unroll
    for (int r = 0; r < 4; ++r) {
        int c = c0 + ty + r * 8;
        tile[ty + r * 8][tx] = dec[((size_t)b * CDIM + c) * NTOK + n0 + tx];
    }
    __syncthreads();
#pragma unroll
    for (int r = 0; r < 4; ++r) {
        int n = n0 + ty + r * 8;
        float val = tile[tx][ty + r * 8];
        size_t idx = ((size_t)b * NTOK + n) * CDIM + c0 + tx;
        x[idx] = val;
        xb[idx] = f2bf(val);
    }
}

// ---------------- weight transpose fp32 [R,C] -> bf16 [C,R] ----------------
__global__ void k_wtrans(const float* __restrict__ src, short* __restrict__ dst,
                         int R, int C) {
    __shared__ float tile[32][33];
    int c0 = blockIdx.x * 32, r0 = blockIdx.y * 32;
    int tx = threadIdx.x, ty = threadIdx.y;
#pragma unroll
    for (int p = 0; p < 4; ++p)
        tile[ty + p * 8][tx] = src[(size_t)(r0 + ty + p * 8) * C + c0 + tx];
    __syncthreads();
#pragma unroll
    for (int p = 0; p < 4; ++p)
        dst[(size_t)(c0 + ty + p * 8) * R + r0 + tx] = f2bf(tile[tx][ty + p * 8]);
}

// ---------------- pack per-head qkv weights -> [2304,768] bf16 (n = sect*768+h*64+d) ----
__global__ __launch_bounds__(256) void k_packqkv(
    const float* __restrict__ wq1, const float* __restrict__ wk1, const float* __restrict__ wv1,
    const float* __restrict__ wq2, const float* __restrict__ wk2, const float* __restrict__ wv2,
    short* __restrict__ dst1, short* __restrict__ dst2) {
    __shared__ float tile[64][65];
    int z = blockIdx.y;                 // 0..71
    int set = z / 36, rem = z % 36, sect = rem / 12, h = rem % 12;
    const float* srcs[6] = {wq1, wk1, wv1, wq2, wk2, wv2};
    const float* src = srcs[set * 3 + sect] + (size_t)h * 768 * 64;
    short* dst = (set ? dst2 : dst1) + ((size_t)sect * 768 + h * 64) * 768;
    int k0 = blockIdx.x * 64;
    int t = threadIdx.x;
#pragma unroll
    for (int p = 0; p < 16; ++p) {
        int gid = t + p * 256;
        int r = gid >> 6, c = gid & 63;
        tile[r][c] = src[(size_t)(k0 + r) * 64 + c];
    }
    __syncthreads();
#pragma unroll
    for (int p = 0; p < 16; ++p) {
        int gid = t + p * 256;
        int d = gid >> 6, kk = gid & 63;
        dst[(size_t)d * 768 + k0 + kk] = f2bf(tile[kk][d]);
    }
}

__global__ void k_packbias(const float* __restrict__ bq1, const float* __restrict__ bk1,
                           const float* __restrict__ bv1, const float* __restrict__ bq2,
                           const float* __restrict__ bk2, const float* __restrict__ bv2,
                           float* __restrict__ d1, float* __restrict__ d2) {
    int tid = blockIdx.x * 256 + threadIdx.x;
    if (tid >= 4608) return;
    int set = tid / 2304, n = tid % 2304;
    int sect = n / 768, rem = n % 768;
    const float* srcs[6] = {bq1, bk1, bv1, bq2, bk2, bv2};
    float v = srcs[set * 3 + sect][rem];
    (set ? d2 : d1)[n] = v;
}

// ---------------- generic bf16 MFMA GEMM, 128xBN tile ----------------
// Single-barrier double-buffered DMA pipeline: barrier drains stage st's DMA,
// then DMA for k+32 into stage st^1 flies DURING the MFMA burst on stage st.
// A [M,K] bf16 row-major; Bt [N,K] bf16 row-major (i.e. B transposed)
#define GM_FINAL 0
#define GM_PROJ  1
#define GM_GELU  2
#define GM_QKV   3
#define QKVSEC ((size_t)BATCH * NH * NTOK * HDIM)  // 6291456

template<int MODE, int BN>
__global__ __launch_bounds__(256) void k_gemm_mfma(
    const short* __restrict__ A, const short* __restrict__ Bt,
    const float* __restrict__ bias, const float* __restrict__ resid,
    const float* __restrict__ rscale, const float* __restrict__ alph,
    float* __restrict__ outF, short* __restrict__ outB, int M, int N, int K) {
    constexpr int NT = BN / 32;   // 16-col tiles per wave
    constexpr int BP = BN / 64;   // B staging passes per 32-chunk
    constexpr int STAGE = 2 * 128 * 32 + 2 * BN * 32;            // shorts (2 stages)
    constexpr int FINALS = (MODE == GM_FINAL) ? 64 * 132 * 2 : 0; // shorts (64 cols x 132-stride floats)
    constexpr int SMEM = STAGE > FINALS ? STAGE : FINALS;
    __shared__ short smem[SMEM];
    short* As = smem;                     // [2][128][32]
    short* Bs = smem + 2 * 128 * 32;      // [2][BN][32]
    int t = threadIdx.x;
    int w = t >> 6, lane = t & 63, l15 = lane & 15, quad = lane >> 4;
    int r0 = blockIdx.x * 128, n0 = blockIdx.y * BN;
    int wr = (w >> 1) * 64, wc = (w & 1) * (BN / 2);
    f32x4 acc[4][NT];
#pragma unroll
    for (int i = 0; i < 4; ++i)
#pragma unroll
        for (int j = 0; j < NT; ++j) acc[i][j] = (f32x4){0.f, 0.f, 0.f, 0.f};
    int sr = t >> 2, sc = (t & 3) * 8;
    const short* Ag = A + (size_t)(r0 + sr) * K + sc;
    const short* Bg = Bt + (size_t)(n0 + sr) * K + sc;
    short* AsW = As + w * 512;   // wave-uniform base: lane l -> + l*8 shorts (16 B)
    short* BsW = Bs + w * 512;
    // preload chunk 0 into stage 0
#pragma unroll
    for (int p = 0; p < 2; ++p)
        async_copy16(Ag, AsW + p * 2048), Ag += (size_t)64 * K * 0;  // (no-op keep Ag)
#pragma unroll
    for (int p = 0; p < 2; ++p)
        ;  // placeholder removed below
    // (real preload)
#pragma unroll
    for (int p = 0; p < 2; ++p)
        async_copy16(Ag + (size_t)p * 64 * K, AsW + p * 2048);
#pragma unroll
    for (int p = 0; p < BP; ++p)
        async_copy16(Bg + (size_t)p * 64 * K, BsW + p * 2048);
    int st = 0;
    for (int k0 = 0; k0 < K; k0 += 32, st ^= 1) {
        __syncthreads();   // drains stage-st DMA; prior stage reads complete
        if (k0 + 32 < K) {
            int nst = st ^ 1;
#pragma unroll
            for (int p = 0; p < 2; ++p)
                async_copy16(Ag + k0 + 32 + (size_t)p * 64 * K,
                             AsW + nst * 4096 + p * 2048);
#pragma unroll
            for (int p = 0; p < BP; ++p)
                async_copy16(Bg + k0 + 32 + (size_t)p * 64 * K,
                             BsW + nst * (BN * 32) + p * 2048);
        }
        bf16x8 af[4], bf[NT];
#pragma unroll
        for (int i = 0; i < 4; ++i)
            af[i] = *(const bf16x8*)&As[st * 4096 + (wr + i * 16 + l15) * 32 + quad * 8];
#pragma unroll
        for (int j = 0; j < NT; ++j)
            bf[j] = *(const bf16x8*)&Bs[st * (BN * 32) + (wc + j * 16 + l15) * 32 + quad * 8];
#pragma unroll
        for (int i = 0; i < 4; ++i)
#pragma unroll
            for (int j = 0; j < NT; ++j)
                acc[i][j] = __builtin_amdgcn_mfma_f32_16x16x32_bf16(af[i], bf[j], acc[i][j], 0, 0, 0);
    }
    if (MODE == GM_FINAL) {
        // fused: val = rscale*val(+bias) + alph*resid; write transposed [B,C,N] via LDS
        __syncthreads();
        float* T = (float*)smem;
#pragma unroll
        for (int i = 0; i < 4; ++i)
#pragma unroll
            for (int j = 0; j < NT; ++j)
#pragma unroll
                for (int rr = 0; rr < 4; ++rr) {
                    int rl = wr + i * 16 + quad * 4 + rr;   // 0..127
                    int cl = wc + j * 16 + l15;             // 0..63
                    int row = r0 + rl, col = n0 + cl;
                    float val = acc[i][j][rr] + bias[col];
                    val = rscale[col] * val + alph[col] * resid[(size_t)row * N + col];
                    T[cl * 132 + rl] = val;
                }
        __syncthreads();
        int c = t >> 2, qo = (t & 3) * 32;
        int b = r0 >> 10, tokbase = r0 & 1023;
        float* obase = outF + ((size_t)(b * 768 + n0 + c)) * 1024 + tokbase + qo;
#pragma unroll
        for (int ii = 0; ii < 8; ++ii)
            *(float4*)&obase[ii * 4] = *(float4*)&T[c * 132 + qo + ii * 4];
        return;
    }
#pragma unroll
    for (int i = 0; i < 4; ++i)
#pragma unroll
        for (int j = 0; j < NT; ++j)
#pragma unroll
            for (int rr = 0; rr < 4; ++rr) {
                int row = r0 + wr + i * 16 + quad * 4 + rr;
                int col = n0 + wc + j * 16 + l15;
                float val = acc[i][j][rr] + bias[col];
                if (MODE == GM_PROJ) {
                    val += rscale[col] * resid[(size_t)row * N + col];
                    outF[(size_t)row * N + col] = val;
                } else if (MODE == GM_GELU) {
                    // tanh-form GELU via hw exp2/rcp: x*sigmoid(1.595769*(x+0.044715x^3))
                    float u = val * (1.0f + 0.044715f * val * val);
                    float zz = __builtin_amdgcn_rcpf(
                        1.0f + __builtin_amdgcn_exp2f(-2.3022082f * u));
                    outB[(size_t)row * N + col] = f2bf(val * zz);
                } else {  // GM_QKV: scatter into q/k/v [B,H,N,64]
                    int sect = col / 768, rem = col - sect * 768;
                    int hh = rem >> 6, d = rem & 63;
                    int bb = row >> 10, tok = row & 1023;
                    outB[(size_t)sect * QKVSEC +
                         (((size_t)bb * NH + hh) * NTOK + tok) * HDIM + d] = f2bf(val);
                }
            }
}

// ---------------- MFMA sigmoid attention ----------------
// per (b,h): O = sigmoid(QK^T/8) V ; q/k/v [B,H,N,64] bf16; O -> [B,N,C] bf16
__global__ __launch_bounds__(256) void k_attn_mfma(
    const short* __restrict__ q, const short* __restrict__ k,
    const short* __restrict__ v, short* __restrict__ o) {
    __shared__ short Ks[64][72];
    __shared__ short Vt[64][72];
    __shared__ short Ps[128][72];
    int b = blockIdx.z, h = blockIdx.y;
    int q0 = blockIdx.x * 128;
    int t = threadIdx.x;
    int w = t >> 6, lane = t & 63, l15 = lane & 15, quad = lane >> 4;
    size_t base = ((size_t)(b * NH + h)) * NTOK * HDIM;
    const short* qp = q + base;
    const short* kp = k + base;
    const short* vp = v + base;
    bf16x8 qf[2][2];
#pragma unroll
    for (int mt = 0; mt < 2; ++mt)
#pragma unroll
        for (int kc = 0; kc < 2; ++kc)
            qf[mt][kc] = *(const bf16x8*)&qp[(size_t)(q0 + w * 32 + mt * 16 + l15) * HDIM + kc * 32 + quad * 8];
    f32x4 oacc[2][4];
#pragma unroll
    for (int mt = 0; mt < 2; ++mt)
#pragma unroll
        for (int dt = 0; dt < 4; ++dt) oacc[mt][dt] = (f32x4){0.f, 0.f, 0.f, 0.f};
    for (int kt = 0; kt < 16; ++kt) {
        __syncthreads();
#pragma unroll
        for (int p = 0; p < 2; ++p) {
            int gid = t + p * 256;
            int r = gid >> 3, c8 = (gid & 7) * 8;
            *(bf16x8*)&Ks[r][c8] = *(const bf16x8*)&kp[(size_t)(kt * 64 + r) * HDIM + c8];
        }
#pragma unroll
        for (int p = 0; p < 2; ++p) {
            int tok = t & 63, d0 = (t >> 6) * 8 + p * 32;
            bf16x8 vv = *(const bf16x8*)&vp[(size_t)(kt * 64 + tok) * HDIM + d0];
#pragma unroll
            for (int j = 0; j < 8; ++j) Vt[d0 + j][tok] = vv[j];
        }
        __syncthreads();
        // S = Q K^T for this wave's 32 q-rows x 64 keys
        f32x4 sacc[2][4];
#pragma unroll
        for (int mt = 0; mt < 2; ++mt)
#pragma unroll
            for (int nt = 0; nt < 4; ++nt) sacc[mt][nt] = (f32x4){0.f, 0.f, 0.f, 0.f};
#pragma unroll
        for (int nt = 0; nt < 4; ++nt) {
            bf16x8 kf0 = *(const bf16x8*)&Ks[nt * 16 + l15][quad * 8];
            bf16x8 kf1 = *(const bf16x8*)&Ks[nt * 16 + l15][32 + quad * 8];
#pragma unroll
            for (int mt = 0; mt < 2; ++mt) {
                sacc[mt][nt] = __builtin_amdgcn_mfma_f32_16x16x32_bf16(qf[mt][0], kf0, sacc[mt][nt], 0, 0, 0);
                sacc[mt][nt] = __builtin_amdgcn_mfma_f32_16x16x32_bf16(qf[mt][1], kf1, sacc[mt][nt], 0, 0, 0);
            }
        }
        // sigmoid -> P (bf16, LDS round-trip to A-operand layout); rows wave-private
#pragma unroll
        for (int mt = 0; mt < 2; ++mt)
#pragma unroll
            for (int nt = 0; nt < 4; ++nt)
#pragma unroll
                for (int rr = 0; rr < 4; ++rr) {
                    float s = sacc[mt][nt][rr];
                    float z = __builtin_amdgcn_rcpf(
                        1.0f + __builtin_amdgcn_exp2f(s * -0.18033688011112042f));
                    Ps[w * 32 + mt * 16 + quad * 4 + rr][nt * 16 + l15] = f2bf(z);
                }
        __syncthreads();
        // O += P V
        bf16x8 vfr[2][4];
#pragma unroll
        for (int kc = 0; kc < 2; ++kc)
#pragma unroll
            for (int dt = 0; dt < 4; ++dt)
                vfr[kc][dt] = *(const bf16x8*)&Vt[dt * 16 + l15][kc * 32 + quad * 8];
#pragma unroll
        for (int mt = 0; mt < 2; ++mt)
#pragma unroll
            for (int kc = 0; kc < 2; ++kc) {
                bf16x8 pf = *(const bf16x8*)&Ps[w * 32 + mt * 16 + l15][kc * 32 + quad * 8];
#pragma unroll
                for (int dt = 0; dt < 4; ++dt)
                    oacc[mt][dt] = __builtin_amdgcn_mfma_f32_16x16x32_bf16(pf, vfr[kc][dt], oacc[mt][dt], 0, 0, 0);
            }
    }
#pragma unroll
    for (int mt = 0; mt < 2; ++mt)
#pragma unroll
        for (int dt = 0; dt < 4; ++dt)
#pragma unroll
            for (int rr = 0; rr < 4; ++rr) {
                int tok = q0 + w * 32 + mt * 16 + quad * 4 + rr;
                int c = h * 64 + dt * 16 + l15;
                o[((size_t)b * NTOK + tok) * CDIM + c] = f2bf(oacc[mt][dt][rr]);
            }
}

// ---------------- depthwise conv, register sliding window (fp32) ----------------
template<int K>
__global__ __launch_bounds__(256) void k_dwconv_t(
    const float* __restrict__ in, const float* __restrict__ w,
    const float* __restrict__ bias, float* __restrict__ out) {
    constexpr int PAD = K / 2;
    constexpr int KK = K * K;
    int t = threadIdx.x;
    int c = blockIdx.y * 64 + (t & 63);
    int j = blockIdx.x * 4 + (t >> 6);
    int b = blockIdx.z;
    float wr[KK];
#pragma unroll
    for (int qq = 0; qq < KK; ++qq) wr[qq] = w[(size_t)c * KK + qq];
    float bsv = bias[c];
    const float* base = in + (size_t)b * NTOK * CDIM + c;
    float win[K][K];
#pragma unroll
    for (int s = 1; s < K; ++s) {
        int ii = s - 1 - PAD;
#pragma unroll
        for (int qq = 0; qq < K; ++qq) {
            int jj = j - PAD + qq;
            win[s][qq] = (ii >= 0 && jj >= 0 && jj < 32)
                         ? base[(size_t)(ii * 32 + jj) * CDIM] : 0.0f;
        }
    }
#pragma unroll
    for (int i = 0; i < 32; ++i) {
#pragma unroll
        for (int r = 0; r < K - 1; ++r)
#pragma unroll
            for (int qq = 0; qq < K; ++qq) win[r][qq] = win[r + 1][qq];
        int ii = i + PAD;
#pragma unroll
        for (int qq = 0; qq < K; ++qq) {
            int jj = j - PAD + qq;
            win[K - 1][qq] = (ii < 32 && jj >= 0 && jj < 32)
                             ? base[(size_t)(ii * 32 + jj) * CDIM] : 0.0f;
        }
        float acc = bsv;
#pragma unroll
        for (int r = 0; r < K; ++r)
#pragma unroll
            for (int qq = 0; qq < K; ++qq)
                acc = fmaf(win[r][qq], wr[r * K + qq], acc);
        out[((size_t)b * NTOK + i * 32 + j) * CDIM + c] = acc;
    }
}

// ---------------- layernorm over C=768, nullable fp32/bf16 outputs ----------------
__global__ __launch_bounds__(256) void k_ln(
    const float* __restrict__ in, const float* __restrict__ g,
    const float* __restrict__ b, float* __restrict__ outF, short* __restrict__ outB) {
    int row = blockIdx.x;
    const float* xr = in + (size_t)row * CDIM;
    int t = threadIdx.x;
    float x0 = xr[t], x1 = xr[t + 256], x2 = xr[t + 512];
    float s = x0 + x1 + x2;
    float sq = x0 * x0 + x1 * x1 + x2 * x2;
#pragma unroll
    for (int off = 32; off > 0; off >>= 1) {
        s += __shfl_down(s, off);
        sq += __shfl_down(sq, off);
    }
    __shared__ float ws[4], wq2[4];
    int wid = t >> 6, lane = t & 63;
    if (lane == 0) { ws[wid] = s; wq2[wid] = sq; }
    __syncthreads();
    if (t == 0) {
        float S = ws[0] + ws[1] + ws[2] + ws[3];
        float Q = wq2[0] + wq2[1] + wq2[2] + wq2[3];
        float m = S * (1.0f / CDIM);
        float var = Q * (1.0f / CDIM) - m * m;
        ws[0] = m;
        wq2[0] = rsqrtf(var + 1e-5f);
    }
    __syncthreads();
    float m = ws[0], inv = wq2[0];
    float y0 = (x0 - m) * inv * g[t] + b[t];
    float y1 = (x1 - m) * inv * g[t + 256] + b[t + 256];
    float y2 = (x2 - m) * inv * g[t + 512] + b[t + 512];
    if (outF) {
        float* orow = outF + (size_t)row * CDIM;
        orow[t] = y0; orow[t + 256] = y1; orow[t + 512] = y2;
    }
    if (outB) {
        short* orow = outB + (size_t)row * CDIM;
        orow[t] = f2bf(y0); orow[t + 256] = f2bf(y1); orow[t + 512] = f2bf(y2);
    }
}

extern "C" void kernel_launch(void* const* d_in, const int* in_sizes, int n_in,
                              void* d_out, int out_size, void* d_ws, size_t ws_size,
                              hipStream_t stream) {
    const float* dec = (const float*)d_in[0];
    const float* wq1 = (const float*)d_in[1]; const float* bq1 = (const float*)d_in[2];
    const float* wk1 = (const float*)d_in[3]; const float* bk1 = (const float*)d_in[4];
    const float* wv1 = (const float*)d_in[5]; const float* bv1 = (const float*)d_in[6];
    const float* wo1 = (const float*)d_in[7]; const float* bo1 = (const float*)d_in[8];
    const float* wq2 = (const float*)d_in[9]; const float* bq2 = (const float*)d_in[10];
    const float* wk2 = (const float*)d_in[11]; const float* bk2 = (const float*)d_in[12];
    const float* wv2 = (const float*)d_in[13]; const float* bv2 = (const float*)d_in[14];
    const float* wo2 = (const float*)d_in[15]; const float* bo2 = (const float*)d_in[16];
    const float* alphas1 = (const float*)d_in[17];
    const float* alphas2 = (const float*)d_in[18];
    const float* peg_w = (const float*)d_in[19]; const float* peg_b = (const float*)d_in[20];
    const float* ln1_g = (const float*)d_in[21]; const float* ln1_b = (const float*)d_in[22];
    const float* ln2_g = (const float*)d_in[23]; const float* ln2_b = (const float*)d_in[24];
    const float* cn_dw_w = (const float*)d_in[25]; const float* cn_dw_b = (const float*)d_in[26];
    const float* cn_ln_g = (const float*)d_in[27]; const float* cn_ln_b = (const float*)d_in[28];
    const float* cn_w1 = (const float*)d_in[29]; const float* cn_b1 = (const float*)d_in[30];
    const float* cn_w2 = (const float*)d_in[31]; const float* cn_b2 = (const float*)d_in[32];
    const float* cn_scale = (const float*)d_in[33]; const float* cn_alphas = (const float*)d_in[34];
    float* out = (float*)d_out;

    const size_t S = (size_t)BATCH * NTOK * CDIM;  // 6291456
    float* A0 = (float*)d_ws;
    float* A1 = A0 + S;
    short* Xb  = (short*)(A1 + S);
    short* QKV = Xb + S;            // 3*S bf16 (q | k | v)
    short* Ob  = QKV + 3 * S;
    short* Hb  = Ob + S;            // 2*S bf16
    short* Wqkv1 = Hb + 2 * S;
    short* Wqkv2 = Wqkv1 + 2304 * 768;
    short* WoT1  = Wqkv2 + 2304 * 768;
    short* WoT2  = WoT1 + 768 * 768;
    short* W1T   = WoT2 + 768 * 768;
    short* W2T   = W1T + (size_t)3072 * 768;
    float* bqkv1 = (float*)(W2T + (size_t)768 * 3072);
    float* bqkv2 = bqkv1 + 2304;
    // MLP-time alias (QKV/Ob/Hb regions dead by then):
    short* Hfull = QKV + 2 * S;     // 8192x3072 bf16 = 4S shorts

    dim3 tb(32, 8);
    dim3 dwgrid(8, 12, 8);

    // ---- weight prep (per-launch) ----
    k_packqkv<<<dim3(12, 72), 256, 0, stream>>>(wq1, wk1, wv1, wq2, wk2, wv2, Wqkv1, Wqkv2);
    k_wtrans<<<dim3(24, 24), tb, 0, stream>>>(wo1, WoT1, 768, 768);
    k_wtrans<<<dim3(24, 24), tb, 0, stream>>>(wo2, WoT2, 768, 768);
    k_wtrans<<<dim3(96, 24), tb, 0, stream>>>(cn_w1, W1T, 768, 3072);
    k_wtrans<<<dim3(24, 96), tb, 0, stream>>>(cn_w2, W2T, 3072, 768);
    k_packbias<<<18, 256, 0, stream>>>(bq1, bk1, bv1, bq2, bk2, bv2, bqkv1, bqkv2);

    // ---- x = transpose(decoder), fp32 + bf16 ----
    k_transpose_in<<<dim3(32, 24, 8), tb, 0, stream>>>(dec, A0, Xb);

    // ---- block 1 ----
    k_gemm_mfma<GM_QKV, 128><<<dim3(64, 18), 256, 0, stream>>>(
        Xb, Wqkv1, bqkv1, nullptr, nullptr, nullptr, nullptr, QKV, 8192, 2304, 768);
    k_attn_mfma<<<dim3(8, 12, 8), 256, 0, stream>>>(QKV, QKV + S, QKV + 2 * S, Ob);
    k_gemm_mfma<GM_PROJ, 64><<<dim3(64, 12), 256, 0, stream>>>(
        Ob, WoT1, bo1, A0, alphas1, nullptr, A1, nullptr, 8192, 768, 768);
    k_dwconv_t<3><<<dwgrid, 256, 0, stream>>>(A1, peg_w, peg_b, A0);
    k_ln<<<8192, 256, 0, stream>>>(A0, ln1_g, ln1_b, A1, Xb);

    // ---- block 2 ----
    k_gemm_mfma<GM_QKV, 128><<<dim3(64, 18), 256, 0, stream>>>(
        Xb, Wqkv2, bqkv2, nullptr, nullptr, nullptr, nullptr, QKV, 8192, 2304, 768);
    k_attn_mfma<<<dim3(8, 12, 8), 256, 0, stream>>>(QKV, QKV + S, QKV + 2 * S, Ob);
    k_gemm_mfma<GM_PROJ, 64><<<dim3(64, 12), 256, 0, stream>>>(
        Ob, WoT2, bo2, A1, alphas2, nullptr, A0, nullptr, 8192, 768, 768);
    k_ln<<<8192, 256, 0, stream>>>(A0, ln2_g, ln2_b, A1, nullptr);  // A1 = xln2 (kept)

    // ---- CNBlock head ----
    k_dwconv_t<7><<<dwgrid, 256, 0, stream>>>(A1, cn_dw_w, cn_dw_b, A0);
    k_ln<<<8192, 256, 0, stream>>>(A0, cn_ln_g, cn_ln_b, nullptr, Xb);
    // MLP, full M=8192; down-proj fused with layer-scale residual + output transpose
    k_gemm_mfma<GM_GELU, 128><<<dim3(64, 24), 256, 0, stream>>>(
        Xb, W1T, cn_b1, nullptr, nullptr, nullptr, nullptr, Hfull, 8192, 3072, 768);
    k_gemm_mfma<GM_FINAL, 64><<<dim3(64, 12), 256, 0, stream>>>(
        Hfull, W2T, cn_b2, A1, cn_scale, cn_alphas, out, nullptr, 8192, 768, 3072);
}